// Round 4
// baseline (552.326 us; speedup 1.0000x reference)
//
#include <hip/hip_runtime.h>

// ---------------------------------------------------------------------------
// MambaLayer on MI355X (gfx950).
// Pipeline (all f16 MFMA with fp32 accumulate; scan/elementwise in fp32):
//   1. convert x -> f16; transpose-convert W_in, W_out -> N-major f16 (B^T form)
//   2. GEMM1: xr = x @ W_in        (16384x1024 @ 1024x4096), f16 out
//   3. conv_bc_p1: conv(3)+SiLU -> xc, Bt/Ct = xc @ [W_B|W_C] (fp32 VALU dot),
//      per-chunk scan final states -> fin       [fused, one xc pass]
//   4. scan_p2: carry propagation across chunks (tiny)
//   5. scan_p3_fuse: replay chunk scan -> ys in LDS, then
//      y = (ys + xc*D) * silu(res) -> overwrite xc (f16)
//   6. GEMM2: out = y @ W_out      (16384x2048 @ 2048x1024), fp32 out
//
// R1: gemm_tn: BK 32->64 + XOR-swizzled LDS (conflicts 1.68e7 -> 0; 202->164us)
// R2: scan restructured to 3 wide phases; p3 fused with y-fuse elementwise.
// R3: conv_silu + bc_gemm + scan_p1 fused into conv_bc_p1 (kills the 67MB xc
//     re-read and the underutilized N=32 MFMA GEMM); scan_p2 unrolled.
// ---------------------------------------------------------------------------

typedef _Float16 half8 __attribute__((ext_vector_type(8)));
typedef float floatx4 __attribute__((ext_vector_type(4)));

#define D_MODEL 1024
#define D_INNER 2048
#define SEQ     4096
#define NBATCH  4
#define NROWS   (NBATCH * SEQ)        // 16384
#define CHUNK   16
#define NCHUNK  (SEQ / CHUNK)         // 256 chunks per batch
#define NTASK   (NBATCH * NCHUNK)     // 1024 chunk-tasks

__device__ __forceinline__ void async16(_Float16* lds, const _Float16* g) {
    // global -> LDS direct copy, 16B per lane; LDS dest = wave-uniform base + lane*16
    __builtin_amdgcn_global_load_lds((const __attribute__((address_space(1))) void*)g,
                                     (__attribute__((address_space(3))) void*)lds, 16, 0, 0);
}

__device__ __forceinline__ float siluf(float x) {
    return x / (1.f + __expf(-x));
}

__device__ __forceinline__ float decay_of(const float* A, int s) {
    return __expf(-log1pf(__expf(A[s])));   // exp(-softplus(A[s]))
}

// --------------------------- conversion kernels ----------------------------

__global__ __launch_bounds__(256) void convert_f32_f16(const float* __restrict__ src,
                                                       _Float16* __restrict__ dst) {
    size_t idx = ((size_t)blockIdx.x * 256 + threadIdx.x) * 8;
    float4 a = *(const float4*)(src + idx);
    float4 b = *(const float4*)(src + idx + 4);
    half8 o = {(_Float16)a.x, (_Float16)a.y, (_Float16)a.z, (_Float16)a.w,
               (_Float16)b.x, (_Float16)b.y, (_Float16)b.z, (_Float16)b.w};
    *(half8*)(dst + idx) = o;
}

// src: K x N fp32 (row-major), dst: N x K f16 (row-major)  [i.e. B^T]
__global__ __launch_bounds__(256) void transpose_to_f16(const float* __restrict__ src,
                                                        _Float16* __restrict__ dst,
                                                        int K, int N) {
    __shared__ float tile[32][33];
    int n0 = blockIdx.x * 32, k0 = blockIdx.y * 32;
    int x = threadIdx.x, y = threadIdx.y;   // 32 x 8
#pragma unroll
    for (int r = 0; r < 32; r += 8)
        tile[y + r][x] = src[(size_t)(k0 + y + r) * N + (n0 + x)];
    __syncthreads();
#pragma unroll
    for (int r = 0; r < 32; r += 8)
        dst[(size_t)(n0 + y + r) * K + (k0 + x)] = (_Float16)tile[x][y + r];
}

// WBCT[n][k], n<16 -> W_B[:,n], n>=16 -> W_C[:,n-16]; shape 32 x 2048 f16
__global__ __launch_bounds__(256) void convert_wbct(const float* __restrict__ WB,
                                                    const float* __restrict__ WC,
                                                    _Float16* __restrict__ WBCT) {
    int idx = blockIdx.x * 256 + threadIdx.x;   // 0 .. 65535
    int n = idx >> 11, k = idx & 2047;
    float v = (n < 16) ? WB[k * 16 + n] : WC[k * 16 + (n - 16)];
    WBCT[idx] = (_Float16)v;
}

// ------------------------------- main GEMM ---------------------------------
// C(MxN) = A(MxK) * B(KxN), with B given as BT (NxK row-major). All f16 in,
// fp32 accumulate. 128x128 block tile, BK=64, 4 waves in 2x2 of 64x64.
// LDS layout is XOR-swizzled in 16B chunks: element chunk c of row r lives at
// LDS[r*64 + (c ^ (r&7))*8]. Staging achieves this by permuting the GLOBAL
// source column per lane (global_load_lds dest is pinned to base+lane*16).
template <typename OutT>
__global__ __launch_bounds__(256) void gemm_tn(const _Float16* __restrict__ A,
                                               const _Float16* __restrict__ BT,
                                               OutT* __restrict__ C,
                                               int M, int N, int K) {
    __shared__ __align__(16) _Float16 As[128 * 64];
    __shared__ __align__(16) _Float16 Bs[128 * 64];
    const int tid = threadIdx.x;
    const int wid = tid >> 6, lane = tid & 63;
    const int row0 = blockIdx.y * 128, col0 = blockIdx.x * 128;
    const int wm = (wid & 1) * 64, wn = (wid >> 1) * 64;

    floatx4 acc[4][4] = {};

    const int sr = lane >> 3;                  // 0..7
    const int sc = ((lane & 7) ^ sr) * 8;      // swizzled source col (elements)
    const size_t aBase = (size_t)(row0 + wid * 32 + sr) * K + sc;
    const size_t bBase = (size_t)(col0 + wid * 32 + sr) * K + sc;
    _Float16* ldsA = As + wid * 2048;          // 32 rows * 64 elems
    _Float16* ldsB = Bs + wid * 2048;

    const int fr = lane & 15, q = lane >> 4;
    const int frq = fr & 7;

    for (int k0 = 0; k0 < K; k0 += 64) {
        __syncthreads();
#pragma unroll
        for (int t = 0; t < 4; t++) {
            async16(ldsA + t * 512, A + aBase + (size_t)(t * 8) * K + k0);
            async16(ldsB + t * 512, BT + bBase + (size_t)(t * 8) * K + k0);
        }
        __syncthreads();
#pragma unroll
        for (int kk = 0; kk < 2; kk++) {
            const int sw = (((kk << 2) + q) ^ frq) * 8;   // swizzled chunk offset
            half8 af[4], bf[4];
#pragma unroll
            for (int i = 0; i < 4; i++) {
                af[i] = *(const half8*)(As + (wm + i * 16 + fr) * 64 + sw);
                bf[i] = *(const half8*)(Bs + (wn + i * 16 + fr) * 64 + sw);
            }
#pragma unroll
            for (int i = 0; i < 4; i++)
#pragma unroll
                for (int j = 0; j < 4; j++)
                    acc[i][j] = __builtin_amdgcn_mfma_f32_16x16x32_f16(af[i], bf[j], acc[i][j], 0, 0, 0);
        }
    }

    // C/D layout: col = lane&15, row = (lane>>4)*4 + reg   [measured m89/m91]
    const int er = (lane >> 4) * 4, ec = lane & 15;
#pragma unroll
    for (int i = 0; i < 4; i++)
#pragma unroll
        for (int j = 0; j < 4; j++)
#pragma unroll
            for (int r = 0; r < 4; r++) {
                int row = row0 + wm + i * 16 + er + r;
                int col = col0 + wn + j * 16 + ec;
                C[(size_t)row * N + col] = (OutT)acc[i][j][r];
            }
}

// ------------------- fused conv + silu + Bt/Ct + scan p1 -------------------
// Block = one 16-row chunk (task). 256 threads.
// Phase A: depthwise conv(3)+SiLU on the chunk's 16 rows -> xc (global).
// Phase B: Bt/Ct = xc_chunk @ [W_B|W_C] via fp32 FMA; thread (cg,s) owns a
//          128-col partial for 16 rows. xc re-read through L1 (just written).
// Phase C: shfl cross-cg + LDS cross-wave reduction -> BtCt global; then
//          16-lane chunk scan -> fin.
__global__ __launch_bounds__(256) void conv_bc_p1(const _Float16* __restrict__ xr,
                                                  const float* __restrict__ cw,
                                                  const float* __restrict__ cb,
                                                  const _Float16* __restrict__ WBCT,
                                                  const float* __restrict__ A,
                                                  _Float16* __restrict__ xc,
                                                  float* __restrict__ BtCt,
                                                  float* __restrict__ fin) {
    const int task = blockIdx.x;
    const int b = task >> 8, c = task & (NCHUNK - 1);
    const int row0 = b * SEQ + c * CHUNK;
    const int tid = threadIdx.x;

    // ---- Phase A: conv + silu over 16 rows, thread owns 8 columns ----
    {
        const int col0 = tid * 8;
        float w0[8], w1[8], w2[8], bb[8];
#pragma unroll
        for (int j = 0; j < 8; j++) {
            w0[j] = cw[(col0 + j) * 3];
            w1[j] = cw[(col0 + j) * 3 + 1];
            w2[j] = cw[(col0 + j) * 3 + 2];
            bb[j] = cb[col0 + j];
        }
        half8 prev = {}, cur, next;
        if (c > 0) prev = *(const half8*)(xr + (size_t)(row0 - 1) * 4096 + col0);
        cur = *(const half8*)(xr + (size_t)row0 * 4096 + col0);
#pragma unroll
        for (int r = 0; r < CHUNK; r++) {
            if (c == NCHUNK - 1 && r == CHUNK - 1) {
                half8 z = {};
                next = z;
            } else {
                next = *(const half8*)(xr + (size_t)(row0 + r + 1) * 4096 + col0);
            }
            half8 o;
#pragma unroll
            for (int j = 0; j < 8; j++) {
                float a = (float)prev[j] * w0[j] + (float)cur[j] * w1[j] +
                          (float)next[j] * w2[j] + bb[j];
                o[j] = (_Float16)siluf(a);
            }
            *(half8*)(xc + (size_t)(row0 + r) * D_INNER + col0) = o;
            prev = cur;
            cur = next;
        }
    }
    __syncthreads();   // xc visible via L1/L2 for same-block readers

    // ---- Phase B: 128-col partial dot products, thread = (cg, s) ----
    const int cg = tid >> 4, s = tid & 15;     // cg 0..15, s 0..15
    float accB[CHUNK], accC[CHUNK];
#pragma unroll
    for (int r = 0; r < CHUNK; r++) { accB[r] = 0.f; accC[r] = 0.f; }

    const int colb0 = cg * 128;
#pragma unroll 4
    for (int kc = 0; kc < 16; kc++) {
        const int colb = colb0 + kc * 8;
        half8 wb8 = *(const half8*)(WBCT + (size_t)s * D_INNER + colb);
        half8 wc8 = *(const half8*)(WBCT + (size_t)(16 + s) * D_INNER + colb);
#pragma unroll
        for (int r = 0; r < CHUNK; r++) {
            half8 x8 = *(const half8*)(xc + (size_t)(row0 + r) * D_INNER + colb);
#pragma unroll
            for (int j = 0; j < 8; j++) {
                accB[r] += (float)x8[j] * (float)wb8[j];
                accC[r] += (float)x8[j] * (float)wc8[j];
            }
        }
    }

    // ---- Phase C: reduce over cg (4 in-wave via shfl, 4 waves via LDS) ----
    __shared__ float red[4 * CHUNK * 32];      // [wave][row][32 outs], 8KB
    __shared__ float btl[CHUNK * 32];          // final Bt|Ct for scan, 2KB
    const int wid = tid >> 6, lane = tid & 63;
#pragma unroll
    for (int r = 0; r < CHUNK; r++) {
        float vb = accB[r], vc = accC[r];
        vb += __shfl_xor(vb, 16); vb += __shfl_xor(vb, 32);
        vc += __shfl_xor(vc, 16); vc += __shfl_xor(vc, 32);
        if ((lane >> 4) == 0) {                // lanes 0..15 hold s = lane
            red[wid * (CHUNK * 32) + r * 32 + s] = vb;
            red[wid * (CHUNK * 32) + r * 32 + 16 + s] = vc;
        }
    }
    __syncthreads();
#pragma unroll
    for (int i = 0; i < 2; i++) {
        int idx = tid * 2 + i;                 // 0..511 -> (r, o)
        int r = idx >> 5, o = idx & 31;
        float v = red[r * 32 + o] + red[(CHUNK * 32) + r * 32 + o] +
                  red[2 * (CHUNK * 32) + r * 32 + o] + red[3 * (CHUNK * 32) + r * 32 + o];
        btl[idx] = v;
        BtCt[(size_t)(row0 + r) * 32 + o] = v;
    }
    __syncthreads();
    if (tid < 16) {
        const float decay = decay_of(A, tid);
        float st = 0.f;
#pragma unroll
        for (int r = 0; r < CHUNK; r++)
            st = st * decay + btl[r * 32 + tid];
        fin[task * 16 + tid] = st;
    }
}

// -------------------------------- scan -------------------------------------
// phase 2: carry propagation across chunks. 1 block x 64 threads (b,s).
__global__ __launch_bounds__(64) void scan_p2(const float* __restrict__ fin,
                                              const float* __restrict__ A,
                                              float* __restrict__ carry) {
    int t = threadIdx.x;
    int b = t >> 4, s = t & 15;
    float decay = decay_of(A, s);
    float d16 = decay;
#pragma unroll
    for (int k = 0; k < 4; k++) d16 *= d16;     // decay^16
    float cy = 0.f;
#pragma unroll 8
    for (int c = 0; c < NCHUNK; c++) {
        int idx = ((b * NCHUNK) + c) * 16 + s;
        carry[idx] = cy;
        cy = cy * d16 + fin[idx];
    }
}

// phase 3 + y-fuse: replay chunk scan (lanes 0..15) -> ys in LDS, then all
// 256 threads compute y = (ys + xc*D) * silu(res), overwriting xc (f16).
// 1024 blocks x 256 threads; block = chunk-task (16 rows).
__global__ __launch_bounds__(256) void scan_p3_fuse(const float* __restrict__ BtCt,
                                                    const float* __restrict__ A,
                                                    const float* __restrict__ carry,
                                                    const float* __restrict__ D,
                                                    const _Float16* __restrict__ xr,
                                                    _Float16* __restrict__ xc) {
    __shared__ float ysl[CHUNK];
    const int task = blockIdx.x;
    const int b = task >> 8, c = task & (NCHUNK - 1);
    const int row0 = b * SEQ + c * CHUNK;
    const int tid = threadIdx.x;

    if (tid < 16) {
        const int s = tid;
        const float decay = decay_of(A, s);
        float st = carry[task * 16 + s];
        size_t r = (size_t)row0 * 32;
#pragma unroll
        for (int j = 0; j < CHUNK; j++) {
            st = st * decay + BtCt[r + s];
            float y = st * BtCt[r + 16 + s];
            y += __shfl_xor(y, 1, 16);
            y += __shfl_xor(y, 2, 16);
            y += __shfl_xor(y, 4, 16);
            y += __shfl_xor(y, 8, 16);
            if (s == 0) ysl[j] = y;
            r += 32;
        }
    }
    __syncthreads();

#pragma unroll
    for (int it = 0; it < 16; it++) {
        int chunk = it * 256 + tid;            // 0..4095 (16 rows x 256 col-chunks)
        int rl = chunk >> 8;                   // row within chunk
        int colb = (chunk & 255) * 8;          // col offset (elements)
        size_t row = (size_t)(row0 + rl);
        float yv = ysl[rl];
        half8 x8 = *(const half8*)(xc + row * D_INNER + colb);
        half8 r8 = *(const half8*)(xr + row * 4096 + 2048 + colb);
        float4 d0 = *(const float4*)(D + colb);
        float4 d1 = *(const float4*)(D + colb + 4);
        half8 o;
        float dd[8] = {d0.x, d0.y, d0.z, d0.w, d1.x, d1.y, d1.z, d1.w};
#pragma unroll
        for (int j = 0; j < 8; j++) {
            float y = yv + (float)x8[j] * dd[j];
            o[j] = (_Float16)(y * siluf((float)r8[j]));
        }
        *(half8*)(xc + row * D_INNER + colb) = o;
    }
}

// ------------------------------- launcher ----------------------------------
extern "C" void kernel_launch(void* const* d_in, const int* in_sizes, int n_in,
                              void* d_out, int out_size, void* d_ws, size_t ws_size,
                              hipStream_t stream) {
    const float* x      = (const float*)d_in[0];
    const float* W_in   = (const float*)d_in[1];
    const float* conv_w = (const float*)d_in[2];
    const float* conv_b = (const float*)d_in[3];
    const float* W_B    = (const float*)d_in[4];
    const float* W_C    = (const float*)d_in[5];
    const float* A      = (const float*)d_in[6];
    const float* D      = (const float*)d_in[7];
    const float* W_out  = (const float*)d_in[8];
    float* out = (float*)d_out;

    char* ws = (char*)d_ws;
    size_t off = 0;
    auto alloc = [&](size_t bytes) { size_t o = off; off += (bytes + 255) & ~(size_t)255; return o; };
    _Float16* xh    = (_Float16*)(ws + alloc((size_t)NROWS * D_MODEL * 2));      // 33.5 MB
    _Float16* WinT  = (_Float16*)(ws + alloc((size_t)4096 * 1024 * 2));          //  8.4 MB
    _Float16* WoutT = (_Float16*)(ws + alloc((size_t)1024 * 2048 * 2));          //  4.2 MB
    _Float16* WBCT  = (_Float16*)(ws + alloc((size_t)32 * 2048 * 2));            //  0.13 MB
    _Float16* xr    = (_Float16*)(ws + alloc((size_t)NROWS * 4096 * 2));         //  134 MB
    _Float16* xc    = (_Float16*)(ws + alloc((size_t)NROWS * D_INNER * 2));      //   67 MB
    float*    BtCt  = (float*)(ws + alloc((size_t)NROWS * 32 * 4));              //    2 MB
    float*    fin   = (float*)(ws + alloc((size_t)NTASK * 16 * 4));              //  64 KB
    float*    carry = (float*)(ws + alloc((size_t)NTASK * 16 * 4));              //  64 KB

    // 1. conversions
    convert_f32_f16<<<(NROWS * D_MODEL) / (256 * 8), 256, 0, stream>>>(x, xh);
    transpose_to_f16<<<dim3(4096 / 32, 1024 / 32), dim3(32, 8), 0, stream>>>(W_in, WinT, 1024, 4096);
    transpose_to_f16<<<dim3(1024 / 32, 2048 / 32), dim3(32, 8), 0, stream>>>(W_out, WoutT, 2048, 1024);
    convert_wbct<<<(32 * 2048) / 256, 256, 0, stream>>>(W_B, W_C, WBCT);
    // 2. GEMM1: xr = x @ W_in
    gemm_tn<_Float16><<<dim3(4096 / 128, NROWS / 128), 256, 0, stream>>>(xh, WinT, xr, NROWS, 4096, 1024);
    // 3. conv + silu + Bt/Ct + scan phase 1 (fused)
    conv_bc_p1<<<NTASK, 256, 0, stream>>>(xr, conv_w, conv_b, WBCT, A, xc, BtCt, fin);
    // 4. scan phase 2
    scan_p2<<<1, 64, 0, stream>>>(fin, A, carry);
    // 5. scan phase 3 + y-fuse
    scan_p3_fuse<<<NTASK, 256, 0, stream>>>(BtCt, A, carry, D, xr, xc);
    // 6. GEMM2: out = y @ W_out
    gemm_tn<float><<<dim3(1024 / 128, NROWS / 128), 256, 0, stream>>>(xc, WoutT, out, NROWS, 1024, 2048);
}

// Round 5
// 508.155 us; speedup vs baseline: 1.0869x; 1.0869x over previous
//
#include <hip/hip_runtime.h>

// ---------------------------------------------------------------------------
// MambaLayer on MI355X (gfx950).
// Pipeline (all f16 MFMA with fp32 accumulate; scan/elementwise in fp32):
//   1. convert x -> f16; transpose-convert W_in, W_out -> N-major f16 (B^T form)
//   2. GEMM1: xr = x @ W_in        (16384x1024 @ 1024x4096), f16 out
//   3. conv_silu_chunk: conv(3)+SiLU -> xc (16 rows/block, register rolling)
//   4. bc_gemm split-K=2: BtCt = xc @ [W_B|W_C] (MFMA, atomicAdd epilogue)
//   5. scan_p1/p2: per-chunk states + carry propagation (wide grids)
//   6. scan_p3_fuse: replay chunk scan (reg-preloaded) -> ys in LDS, then
//      y = (ys + xc*D) * silu(res) -> overwrite xc (f16)
//   7. GEMM2: out = y @ W_out      (16384x2048 @ 2048x1024), fp32 out
//
// R1: gemm_tn: BK 32->64 + XOR-swizzled LDS (conflicts 1.68e7 -> 0; 202->164us)
// R2: scan restructured to 3 wide phases; p3 fused with y-fuse elementwise.
// R3: FAILED (+34us): VALU-dot fusion of conv+bc+p1 — broadcast loads moved
//     bc off the MFMA pipe and serialized ~21us of VALU behind conv. Reverted.
// R4: chunked conv (3x -> 1.06x row reads); bc_gemm split-K=2 (2 blk/CU hides
//     barrier-drain latency); p3 scan prologue reg-preloaded (no serial L2 chain).
// ---------------------------------------------------------------------------

typedef _Float16 half8 __attribute__((ext_vector_type(8)));
typedef float floatx4 __attribute__((ext_vector_type(4)));

#define D_MODEL 1024
#define D_INNER 2048
#define SEQ     4096
#define NBATCH  4
#define NROWS   (NBATCH * SEQ)        // 16384
#define CHUNK   16
#define NCHUNK  (SEQ / CHUNK)         // 256 chunks per batch
#define NTASK   (NBATCH * NCHUNK)     // 1024 chunk-tasks

__device__ __forceinline__ void async16(_Float16* lds, const _Float16* g) {
    // global -> LDS direct copy, 16B per lane; LDS dest = wave-uniform base + lane*16
    __builtin_amdgcn_global_load_lds((const __attribute__((address_space(1))) void*)g,
                                     (__attribute__((address_space(3))) void*)lds, 16, 0, 0);
}

__device__ __forceinline__ float siluf(float x) {
    return x / (1.f + __expf(-x));
}

__device__ __forceinline__ float decay_of(const float* A, int s) {
    return __expf(-log1pf(__expf(A[s])));   // exp(-softplus(A[s]))
}

// --------------------------- conversion kernels ----------------------------

__global__ __launch_bounds__(256) void convert_f32_f16(const float* __restrict__ src,
                                                       _Float16* __restrict__ dst) {
    size_t idx = ((size_t)blockIdx.x * 256 + threadIdx.x) * 8;
    float4 a = *(const float4*)(src + idx);
    float4 b = *(const float4*)(src + idx + 4);
    half8 o = {(_Float16)a.x, (_Float16)a.y, (_Float16)a.z, (_Float16)a.w,
               (_Float16)b.x, (_Float16)b.y, (_Float16)b.z, (_Float16)b.w};
    *(half8*)(dst + idx) = o;
}

// src: K x N fp32 (row-major), dst: N x K f16 (row-major)  [i.e. B^T]
__global__ __launch_bounds__(256) void transpose_to_f16(const float* __restrict__ src,
                                                        _Float16* __restrict__ dst,
                                                        int K, int N) {
    __shared__ float tile[32][33];
    int n0 = blockIdx.x * 32, k0 = blockIdx.y * 32;
    int x = threadIdx.x, y = threadIdx.y;   // 32 x 8
#pragma unroll
    for (int r = 0; r < 32; r += 8)
        tile[y + r][x] = src[(size_t)(k0 + y + r) * N + (n0 + x)];
    __syncthreads();
#pragma unroll
    for (int r = 0; r < 32; r += 8)
        dst[(size_t)(n0 + y + r) * K + (k0 + x)] = (_Float16)tile[x][y + r];
}

// WBCT[n][k], n<16 -> W_B[:,n], n>=16 -> W_C[:,n-16]; shape 32 x 2048 f16
__global__ __launch_bounds__(256) void convert_wbct(const float* __restrict__ WB,
                                                    const float* __restrict__ WC,
                                                    _Float16* __restrict__ WBCT) {
    int idx = blockIdx.x * 256 + threadIdx.x;   // 0 .. 65535
    int n = idx >> 11, k = idx & 2047;
    float v = (n < 16) ? WB[k * 16 + n] : WC[k * 16 + (n - 16)];
    WBCT[idx] = (_Float16)v;
}

// zero-fill fp32 buffer (float4 per thread)
__global__ __launch_bounds__(256) void zero_f32(float* __restrict__ p) {
    size_t idx = ((size_t)blockIdx.x * 256 + threadIdx.x) * 4;
    float4 z = {0.f, 0.f, 0.f, 0.f};
    *(float4*)(p + idx) = z;
}

// ------------------------------- main GEMM ---------------------------------
// C(MxN) = A(MxK) * B(KxN), with B given as BT (NxK row-major). All f16 in,
// fp32 accumulate. 128x128 block tile, BK=64, 4 waves in 2x2 of 64x64.
// LDS layout is XOR-swizzled in 16B chunks: element chunk c of row r lives at
// LDS[r*64 + (c ^ (r&7))*8]. Staging achieves this by permuting the GLOBAL
// source column per lane (global_load_lds dest is pinned to base+lane*16).
template <typename OutT>
__global__ __launch_bounds__(256) void gemm_tn(const _Float16* __restrict__ A,
                                               const _Float16* __restrict__ BT,
                                               OutT* __restrict__ C,
                                               int M, int N, int K) {
    __shared__ __align__(16) _Float16 As[128 * 64];
    __shared__ __align__(16) _Float16 Bs[128 * 64];
    const int tid = threadIdx.x;
    const int wid = tid >> 6, lane = tid & 63;
    const int row0 = blockIdx.y * 128, col0 = blockIdx.x * 128;
    const int wm = (wid & 1) * 64, wn = (wid >> 1) * 64;

    floatx4 acc[4][4] = {};

    const int sr = lane >> 3;                  // 0..7
    const int sc = ((lane & 7) ^ sr) * 8;      // swizzled source col (elements)
    const size_t aBase = (size_t)(row0 + wid * 32 + sr) * K + sc;
    const size_t bBase = (size_t)(col0 + wid * 32 + sr) * K + sc;
    _Float16* ldsA = As + wid * 2048;          // 32 rows * 64 elems
    _Float16* ldsB = Bs + wid * 2048;

    const int fr = lane & 15, q = lane >> 4;
    const int frq = fr & 7;

    for (int k0 = 0; k0 < K; k0 += 64) {
        __syncthreads();
#pragma unroll
        for (int t = 0; t < 4; t++) {
            async16(ldsA + t * 512, A + aBase + (size_t)(t * 8) * K + k0);
            async16(ldsB + t * 512, BT + bBase + (size_t)(t * 8) * K + k0);
        }
        __syncthreads();
#pragma unroll
        for (int kk = 0; kk < 2; kk++) {
            const int sw = (((kk << 2) + q) ^ frq) * 8;   // swizzled chunk offset
            half8 af[4], bf[4];
#pragma unroll
            for (int i = 0; i < 4; i++) {
                af[i] = *(const half8*)(As + (wm + i * 16 + fr) * 64 + sw);
                bf[i] = *(const half8*)(Bs + (wn + i * 16 + fr) * 64 + sw);
            }
#pragma unroll
            for (int i = 0; i < 4; i++)
#pragma unroll
                for (int j = 0; j < 4; j++)
                    acc[i][j] = __builtin_amdgcn_mfma_f32_16x16x32_f16(af[i], bf[j], acc[i][j], 0, 0, 0);
        }
    }

    // C/D layout: col = lane&15, row = (lane>>4)*4 + reg   [measured m89/m91]
    const int er = (lane >> 4) * 4, ec = lane & 15;
#pragma unroll
    for (int i = 0; i < 4; i++)
#pragma unroll
        for (int j = 0; j < 4; j++)
#pragma unroll
            for (int r = 0; r < 4; r++) {
                int row = row0 + wm + i * 16 + er + r;
                int col = col0 + wn + j * 16 + ec;
                C[(size_t)row * N + col] = (OutT)acc[i][j][r];
            }
}

// ------------------------- skinny GEMM for Bt/Ct ---------------------------
// BtCt(M x 32) += xc(M x Khalf) @ [W_B | W_C]; BT = WBCT (32 x 2048 f16).
// Split-K=2: blockIdx.y selects K half; epilogue atomicAdd (BtCt pre-zeroed).
__global__ __launch_bounds__(256) void bc_gemm(const _Float16* __restrict__ A,
                                               const _Float16* __restrict__ BT,
                                               float* __restrict__ C) {
    const int K = D_INNER;
    __shared__ __align__(16) _Float16 As[64 * 64];
    __shared__ __align__(16) _Float16 Bs[32 * 64];
    const int tid = threadIdx.x, wid = tid >> 6, lane = tid & 63;
    const int row0 = blockIdx.x * 64;
    const int kbeg = blockIdx.y * (K / 2), kend = kbeg + K / 2;
    floatx4 acc[2] = {};

    const int srow = lane >> 3;            // 0..7
    const int scol = (lane & 7) * 8;       // 0..56
    const size_t aOff0 = (size_t)(row0 + wid * 16 + srow) * K + scol;
    const size_t aOff1 = aOff0 + (size_t)8 * K;
    const size_t bOff  = (size_t)(wid * 8 + srow) * K + scol;
    _Float16* ldsA = As + wid * 1024;
    _Float16* ldsB = Bs + wid * 512;
    const int fr = lane & 15, fc = (lane >> 4) * 8;

    for (int k0 = kbeg; k0 < kend; k0 += 64) {
        __syncthreads();
        async16(ldsA,       A + aOff0 + k0);
        async16(ldsA + 512, A + aOff1 + k0);
        async16(ldsB,       BT + bOff + k0);
        __syncthreads();
#pragma unroll
        for (int s = 0; s < 2; s++) {
            half8 af = *(const half8*)(As + (wid * 16 + fr) * 64 + s * 32 + fc);
#pragma unroll
            for (int nj = 0; nj < 2; nj++) {
                half8 bf = *(const half8*)(Bs + (nj * 16 + fr) * 64 + s * 32 + fc);
                acc[nj] = __builtin_amdgcn_mfma_f32_16x16x32_f16(af, bf, acc[nj], 0, 0, 0);
            }
        }
    }
    const int er = (lane >> 4) * 4, ec = lane & 15;
#pragma unroll
    for (int nj = 0; nj < 2; nj++)
#pragma unroll
        for (int r = 0; r < 4; r++)
            atomicAdd(&C[(size_t)(row0 + wid * 16 + er + r) * 32 + nj * 16 + ec], acc[nj][r]);
}

// ----------------------------- conv + silu ---------------------------------
// 16 rows per block, register rolling: each row read ~1.06x instead of 3x.
__global__ __launch_bounds__(256) void conv_silu_chunk(const _Float16* __restrict__ xr,
                                                       const float* __restrict__ cw,
                                                       const float* __restrict__ cb,
                                                       _Float16* __restrict__ xc) {
    const int task = blockIdx.x;
    const int c = task & (NCHUNK - 1);
    const int row0 = (task >> 8) * SEQ + c * CHUNK;
    const int col0 = threadIdx.x * 8;

    float w0[8], w1[8], w2[8], bb[8];
#pragma unroll
    for (int j = 0; j < 8; j++) {
        w0[j] = cw[(col0 + j) * 3];
        w1[j] = cw[(col0 + j) * 3 + 1];
        w2[j] = cw[(col0 + j) * 3 + 2];
        bb[j] = cb[col0 + j];
    }
    half8 prev = {}, cur, next;
    if (c > 0) prev = *(const half8*)(xr + (size_t)(row0 - 1) * 4096 + col0);
    cur = *(const half8*)(xr + (size_t)row0 * 4096 + col0);
#pragma unroll
    for (int r = 0; r < CHUNK; r++) {
        if (c == NCHUNK - 1 && r == CHUNK - 1) {
            half8 z = {};
            next = z;
        } else {
            next = *(const half8*)(xr + (size_t)(row0 + r + 1) * 4096 + col0);
        }
        half8 o;
#pragma unroll
        for (int j = 0; j < 8; j++) {
            float a = (float)prev[j] * w0[j] + (float)cur[j] * w1[j] +
                      (float)next[j] * w2[j] + bb[j];
            o[j] = (_Float16)siluf(a);
        }
        *(half8*)(xc + (size_t)(row0 + r) * D_INNER + col0) = o;
        prev = cur;
        cur = next;
    }
}

// -------------------------------- scan -------------------------------------
// state[s] = state[s]*decay[s] + Bt[l,s];  ys[l] = sum_s state[s]*Ct[l,s]
// Chunked 3-phase scan, chunk length 16; NTASK=1024 chunk-tasks x 16 states.

// phase 1: per-chunk final states. 64 blocks x 256 threads.
__global__ __launch_bounds__(256) void scan_p1(const float* __restrict__ BtCt,
                                               const float* __restrict__ A,
                                               float* __restrict__ fin) {
    int g = blockIdx.x * 256 + threadIdx.x;     // 0..16383
    int task = g >> 4, s = g & 15;
    int b = task >> 8, c = task & (NCHUNK - 1);
    const float decay = decay_of(A, s);
    size_t r = ((size_t)b * SEQ + c * CHUNK) * 32;
    float st = 0.f;
#pragma unroll
    for (int j = 0; j < CHUNK; j++)
        st = st * decay + BtCt[r + (size_t)j * 32 + s];
    fin[task * 16 + s] = st;
}

// phase 2: carry propagation across chunks. 1 block x 64 threads (b,s).
__global__ __launch_bounds__(64) void scan_p2(const float* __restrict__ fin,
                                              const float* __restrict__ A,
                                              float* __restrict__ carry) {
    int t = threadIdx.x;
    int b = t >> 4, s = t & 15;
    float decay = decay_of(A, s);
    float d16 = decay;
#pragma unroll
    for (int k = 0; k < 4; k++) d16 *= d16;     // decay^16
    float cy = 0.f;
#pragma unroll 8
    for (int c = 0; c < NCHUNK; c++) {
        int idx = ((b * NCHUNK) + c) * 16 + s;
        carry[idx] = cy;
        cy = cy * d16 + fin[idx];
    }
}

// phase 3 + y-fuse: replay chunk scan (lanes 0..15, Bt/Ct preloaded to regs)
// -> ys in LDS, then all 256 threads compute y = (ys + xc*D) * silu(res),
// overwriting xc (f16). 1024 blocks x 256 threads; block = chunk-task.
__global__ __launch_bounds__(256) void scan_p3_fuse(const float* __restrict__ BtCt,
                                                    const float* __restrict__ A,
                                                    const float* __restrict__ carry,
                                                    const float* __restrict__ D,
                                                    const _Float16* __restrict__ xr,
                                                    _Float16* __restrict__ xc) {
    __shared__ float ysl[CHUNK];
    const int task = blockIdx.x;
    const int b = task >> 8, c = task & (NCHUNK - 1);
    const int row0 = b * SEQ + c * CHUNK;
    const int tid = threadIdx.x;

    if (tid < 16) {
        const int s = tid;
        const float decay = decay_of(A, s);
        size_t r = (size_t)row0 * 32;
        float bt[CHUNK], ct[CHUNK];
#pragma unroll
        for (int j = 0; j < CHUNK; j++) {       // independent loads, ILP
            bt[j] = BtCt[r + (size_t)j * 32 + s];
            ct[j] = BtCt[r + (size_t)j * 32 + 16 + s];
        }
        float st = carry[task * 16 + s];
        float yv[CHUNK];
#pragma unroll
        for (int j = 0; j < CHUNK; j++) {       // serial FMA chain only
            st = st * decay + bt[j];
            yv[j] = st * ct[j];
        }
#pragma unroll
        for (int j = 0; j < CHUNK; j++) {       // 16 independent reduce chains
            float y = yv[j];
            y += __shfl_xor(y, 1, 16);
            y += __shfl_xor(y, 2, 16);
            y += __shfl_xor(y, 4, 16);
            y += __shfl_xor(y, 8, 16);
            if (s == 0) ysl[j] = y;
        }
    }
    __syncthreads();

#pragma unroll
    for (int it = 0; it < 16; it++) {
        int chunk = it * 256 + tid;            // 0..4095 (16 rows x 256 col-chunks)
        int rl = chunk >> 8;                   // row within chunk
        int colb = (chunk & 255) * 8;          // col offset (elements)
        size_t row = (size_t)(row0 + rl);
        float yv = ysl[rl];
        half8 x8 = *(const half8*)(xc + row * D_INNER + colb);
        half8 r8 = *(const half8*)(xr + row * 4096 + 2048 + colb);
        float4 d0 = *(const float4*)(D + colb);
        float4 d1 = *(const float4*)(D + colb + 4);
        half8 o;
        float dd[8] = {d0.x, d0.y, d0.z, d0.w, d1.x, d1.y, d1.z, d1.w};
#pragma unroll
        for (int j = 0; j < 8; j++) {
            float y = yv + (float)x8[j] * dd[j];
            o[j] = (_Float16)(y * siluf((float)r8[j]));
        }
        *(half8*)(xc + row * D_INNER + colb) = o;
    }
}

// ------------------------------- launcher ----------------------------------
extern "C" void kernel_launch(void* const* d_in, const int* in_sizes, int n_in,
                              void* d_out, int out_size, void* d_ws, size_t ws_size,
                              hipStream_t stream) {
    const float* x      = (const float*)d_in[0];
    const float* W_in   = (const float*)d_in[1];
    const float* conv_w = (const float*)d_in[2];
    const float* conv_b = (const float*)d_in[3];
    const float* W_B    = (const float*)d_in[4];
    const float* W_C    = (const float*)d_in[5];
    const float* A      = (const float*)d_in[6];
    const float* D      = (const float*)d_in[7];
    const float* W_out  = (const float*)d_in[8];
    float* out = (float*)d_out;

    char* ws = (char*)d_ws;
    size_t off = 0;
    auto alloc = [&](size_t bytes) { size_t o = off; off += (bytes + 255) & ~(size_t)255; return o; };
    _Float16* xh    = (_Float16*)(ws + alloc((size_t)NROWS * D_MODEL * 2));      // 33.5 MB
    _Float16* WinT  = (_Float16*)(ws + alloc((size_t)4096 * 1024 * 2));          //  8.4 MB
    _Float16* WoutT = (_Float16*)(ws + alloc((size_t)1024 * 2048 * 2));          //  4.2 MB
    _Float16* WBCT  = (_Float16*)(ws + alloc((size_t)32 * 2048 * 2));            //  0.13 MB
    _Float16* xr    = (_Float16*)(ws + alloc((size_t)NROWS * 4096 * 2));         //  134 MB
    _Float16* xc    = (_Float16*)(ws + alloc((size_t)NROWS * D_INNER * 2));      //   67 MB
    float*    BtCt  = (float*)(ws + alloc((size_t)NROWS * 32 * 4));              //    2 MB
    float*    fin   = (float*)(ws + alloc((size_t)NTASK * 16 * 4));              //  64 KB
    float*    carry = (float*)(ws + alloc((size_t)NTASK * 16 * 4));              //  64 KB

    // 1. conversions (+ zero BtCt for split-K atomics)
    convert_f32_f16<<<(NROWS * D_MODEL) / (256 * 8), 256, 0, stream>>>(x, xh);
    transpose_to_f16<<<dim3(4096 / 32, 1024 / 32), dim3(32, 8), 0, stream>>>(W_in, WinT, 1024, 4096);
    transpose_to_f16<<<dim3(1024 / 32, 2048 / 32), dim3(32, 8), 0, stream>>>(W_out, WoutT, 2048, 1024);
    convert_wbct<<<(32 * 2048) / 256, 256, 0, stream>>>(W_B, W_C, WBCT);
    zero_f32<<<(NROWS * 32) / (256 * 4), 256, 0, stream>>>(BtCt);
    // 2. GEMM1: xr = x @ W_in
    gemm_tn<_Float16><<<dim3(4096 / 128, NROWS / 128), 256, 0, stream>>>(xh, WinT, xr, NROWS, 4096, 1024);
    // 3. conv + silu (chunked)
    conv_silu_chunk<<<NTASK, 256, 0, stream>>>(xr, conv_w, conv_b, xc);
    // 4. Bt/Ct projection (split-K=2)
    bc_gemm<<<dim3(NROWS / 64, 2), 256, 0, stream>>>(xc, WBCT, BtCt);
    // 5. scan phases 1-2
    scan_p1<<<NTASK * 16 / 256, 256, 0, stream>>>(BtCt, A, fin);
    scan_p2<<<1, 64, 0, stream>>>(fin, A, carry);
    // 6. scan phase 3 + y-fuse
    scan_p3_fuse<<<NTASK, 256, 0, stream>>>(BtCt, A, carry, D, xr, xc);
    // 7. GEMM2: out = y @ W_out
    gemm_tn<float><<<dim3(1024 / 128, NROWS / 128), 256, 0, stream>>>(xc, WoutT, out, NROWS, 1024, 2048);
}

// Round 6
// 501.551 us; speedup vs baseline: 1.1012x; 1.0132x over previous
//
#include <hip/hip_runtime.h>

// ---------------------------------------------------------------------------
// MambaLayer on MI355X (gfx950).
// Pipeline (all f16 MFMA with fp32 accumulate; scan/elementwise in fp32):
//   1. convert x -> f16; transpose-convert W_in, W_out -> N-major f16 (B^T form)
//   2. GEMM1: xr = x @ W_in  (two half-M launches for profiling visibility)
//   3. conv_bc_fin: conv(3)+SiLU -> xc  AND  BtCt = xc @ [W_B|W_C] (MFMA,
//      per-wave K-split, no main-loop barriers) AND per-chunk fin states
//   4. scan_p2: carry propagation across chunks (tiny)
//   5. scan_p3_fuse: replay chunk scan (reg-preloaded) -> ys in LDS, then
//      y = (ys + xc*D) * silu(res) -> overwrite xc (f16)
//   6. GEMM2: out = y @ W_out      (16384x2048 @ 2048x1024), fp32 out
//
// R1: gemm_tn: BK 32->64 + XOR-swizzled LDS (conflicts 1.68e7 -> 0; 202->164us)
// R2: scan restructured to 3 wide phases; p3 fused with y-fuse elementwise.
// R3: FAILED (+34us): VALU-dot fusion — bc off MFMA pipe + broadcast loads.
// R4: chunked conv, bc split-K=2, p3 reg-preload. 508us.
// R5: conv+bc+p1 fused KEEPING MFMA: 32-row blocks, waves own disjoint K
//     (no barriers in main loop), B-frags direct from L1-hot WBCT; kills the
//     67MB xc re-read + zero/atomics + scan_p1. GEMM1 split 2x for top-5
//     visibility of GEMM2/p3/conv_bc.
// ---------------------------------------------------------------------------

typedef _Float16 half8 __attribute__((ext_vector_type(8)));
typedef float floatx4 __attribute__((ext_vector_type(4)));

#define D_MODEL 1024
#define D_INNER 2048
#define SEQ     4096
#define NBATCH  4
#define NROWS   (NBATCH * SEQ)        // 16384
#define CHUNK   16
#define NCHUNK  (SEQ / CHUNK)         // 256 chunks per batch
#define NTASK   (NBATCH * NCHUNK)     // 1024 chunk-tasks

__device__ __forceinline__ void async16(_Float16* lds, const _Float16* g) {
    // global -> LDS direct copy, 16B per lane; LDS dest = wave-uniform base + lane*16
    __builtin_amdgcn_global_load_lds((const __attribute__((address_space(1))) void*)g,
                                     (__attribute__((address_space(3))) void*)lds, 16, 0, 0);
}

__device__ __forceinline__ float siluf(float x) {
    return x / (1.f + __expf(-x));
}

__device__ __forceinline__ float decay_of(const float* A, int s) {
    return __expf(-log1pf(__expf(A[s])));   // exp(-softplus(A[s]))
}

// --------------------------- conversion kernels ----------------------------

__global__ __launch_bounds__(256) void convert_f32_f16(const float* __restrict__ src,
                                                       _Float16* __restrict__ dst) {
    size_t idx = ((size_t)blockIdx.x * 256 + threadIdx.x) * 8;
    float4 a = *(const float4*)(src + idx);
    float4 b = *(const float4*)(src + idx + 4);
    half8 o = {(_Float16)a.x, (_Float16)a.y, (_Float16)a.z, (_Float16)a.w,
               (_Float16)b.x, (_Float16)b.y, (_Float16)b.z, (_Float16)b.w};
    *(half8*)(dst + idx) = o;
}

// src: K x N fp32 (row-major), dst: N x K f16 (row-major)  [i.e. B^T]
__global__ __launch_bounds__(256) void transpose_to_f16(const float* __restrict__ src,
                                                        _Float16* __restrict__ dst,
                                                        int K, int N) {
    __shared__ float tile[32][33];
    int n0 = blockIdx.x * 32, k0 = blockIdx.y * 32;
    int x = threadIdx.x, y = threadIdx.y;   // 32 x 8
#pragma unroll
    for (int r = 0; r < 32; r += 8)
        tile[y + r][x] = src[(size_t)(k0 + y + r) * N + (n0 + x)];
    __syncthreads();
#pragma unroll
    for (int r = 0; r < 32; r += 8)
        dst[(size_t)(n0 + y + r) * K + (k0 + x)] = (_Float16)tile[x][y + r];
}

// WBCT[n][k], n<16 -> W_B[:,n], n>=16 -> W_C[:,n-16]; shape 32 x 2048 f16
__global__ __launch_bounds__(256) void convert_wbct(const float* __restrict__ WB,
                                                    const float* __restrict__ WC,
                                                    _Float16* __restrict__ WBCT) {
    int idx = blockIdx.x * 256 + threadIdx.x;   // 0 .. 65535
    int n = idx >> 11, k = idx & 2047;
    float v = (n < 16) ? WB[k * 16 + n] : WC[k * 16 + (n - 16)];
    WBCT[idx] = (_Float16)v;
}

// ------------------------------- main GEMM ---------------------------------
// C(MxN) = A(MxK) * B(KxN), with B given as BT (NxK row-major). All f16 in,
// fp32 accumulate. 128x128 block tile, BK=64, 4 waves in 2x2 of 64x64.
// LDS layout is XOR-swizzled in 16B chunks: element chunk c of row r lives at
// LDS[r*64 + (c ^ (r&7))*8]. Staging achieves this by permuting the GLOBAL
// source column per lane (global_load_lds dest is pinned to base+lane*16).
template <typename OutT>
__global__ __launch_bounds__(256) void gemm_tn(const _Float16* __restrict__ A,
                                               const _Float16* __restrict__ BT,
                                               OutT* __restrict__ C,
                                               int M, int N, int K) {
    __shared__ __align__(16) _Float16 As[128 * 64];
    __shared__ __align__(16) _Float16 Bs[128 * 64];
    const int tid = threadIdx.x;
    const int wid = tid >> 6, lane = tid & 63;
    const int row0 = blockIdx.y * 128, col0 = blockIdx.x * 128;
    const int wm = (wid & 1) * 64, wn = (wid >> 1) * 64;

    floatx4 acc[4][4] = {};

    const int sr = lane >> 3;                  // 0..7
    const int sc = ((lane & 7) ^ sr) * 8;      // swizzled source col (elements)
    const size_t aBase = (size_t)(row0 + wid * 32 + sr) * K + sc;
    const size_t bBase = (size_t)(col0 + wid * 32 + sr) * K + sc;
    _Float16* ldsA = As + wid * 2048;          // 32 rows * 64 elems
    _Float16* ldsB = Bs + wid * 2048;

    const int fr = lane & 15, q = lane >> 4;
    const int frq = fr & 7;

    for (int k0 = 0; k0 < K; k0 += 64) {
        __syncthreads();
#pragma unroll
        for (int t = 0; t < 4; t++) {
            async16(ldsA + t * 512, A + aBase + (size_t)(t * 8) * K + k0);
            async16(ldsB + t * 512, BT + bBase + (size_t)(t * 8) * K + k0);
        }
        __syncthreads();
#pragma unroll
        for (int kk = 0; kk < 2; kk++) {
            const int sw = (((kk << 2) + q) ^ frq) * 8;   // swizzled chunk offset
            half8 af[4], bf[4];
#pragma unroll
            for (int i = 0; i < 4; i++) {
                af[i] = *(const half8*)(As + (wm + i * 16 + fr) * 64 + sw);
                bf[i] = *(const half8*)(Bs + (wn + i * 16 + fr) * 64 + sw);
            }
#pragma unroll
            for (int i = 0; i < 4; i++)
#pragma unroll
                for (int j = 0; j < 4; j++)
                    acc[i][j] = __builtin_amdgcn_mfma_f32_16x16x32_f16(af[i], bf[j], acc[i][j], 0, 0, 0);
        }
    }

    // C/D layout: col = lane&15, row = (lane>>4)*4 + reg   [measured m89/m91]
    const int er = (lane >> 4) * 4, ec = lane & 15;
#pragma unroll
    for (int i = 0; i < 4; i++)
#pragma unroll
        for (int j = 0; j < 4; j++)
#pragma unroll
            for (int r = 0; r < 4; r++) {
                int row = row0 + wm + i * 16 + er + r;
                int col = col0 + wn + j * 16 + ec;
                C[(size_t)row * N + col] = (OutT)acc[i][j][r];
            }
}

// ---------------- fused conv + silu + Bt/Ct (MFMA) + scan p1 ----------------
// Block = 32 rows (2 chunks), 256 threads = 4 waves. Waves own disjoint K
// quarters (512 cols = 4 panels of 128) -> NO barriers in the main loop.
// Per panel (per wave): rolling conv+silu 8 rows/lane-group -> write xc +
// ds_write swizzled LDS panel -> 16 MFMA vs B-frags read directly from
// WBCT (128KB, L1/L2-hot). Epilogue: cross-wave LDS reduce -> BtCt + fin.
__global__ __launch_bounds__(256) void conv_bc_fin(const _Float16* __restrict__ xr,
                                                   const float* __restrict__ cw,
                                                   const float* __restrict__ cb,
                                                   const _Float16* __restrict__ WBCT,
                                                   const float* __restrict__ A,
                                                   _Float16* __restrict__ xc,
                                                   float* __restrict__ BtCt,
                                                   float* __restrict__ fin) {
    __shared__ __align__(16) _Float16 As[4 * 32 * 128];   // 32 KB; reused in epilogue
    const int tid = threadIdx.x, wid = tid >> 6, lane = tid & 63;
    const int row0 = blockIdx.x * 32;
    const int l0 = row0 & (SEQ - 1);
    const int cg = lane & 15;            // col-group within panel (8 cols)
    const int rg = lane >> 4;            // row-group (8 rows)
    const int fr = lane & 15, q = lane >> 4;
    _Float16* As_w = As + wid * 4096;
    const int r0 = rg * 8;

    floatx4 acc[2][2] = {};

    for (int t = 0; t < 4; t++) {
        const int kbase = wid * 512 + t * 128;
        const int gcol = kbase + cg * 8;
        float w0[8], w1[8], w2[8], bb[8];
#pragma unroll
        for (int j = 0; j < 8; j++) {
            w0[j] = cw[(gcol + j) * 3];
            w1[j] = cw[(gcol + j) * 3 + 1];
            w2[j] = cw[(gcol + j) * 3 + 2];
            bb[j] = cb[gcol + j];
        }
        half8 prev = {}, cur, nxt;
        if (!(l0 == 0 && rg == 0))
            prev = *(const half8*)(xr + (size_t)(row0 + r0 - 1) * 4096 + gcol);
        cur = *(const half8*)(xr + (size_t)(row0 + r0) * 4096 + gcol);
#pragma unroll
        for (int r = 0; r < 8; r++) {
            if (r == 7 && rg == 3 && l0 + 32 == SEQ) {
                half8 z = {};
                nxt = z;
            } else {
                nxt = *(const half8*)(xr + (size_t)(row0 + r0 + r + 1) * 4096 + gcol);
            }
            half8 o;
#pragma unroll
            for (int j = 0; j < 8; j++) {
                float a = (float)prev[j] * w0[j] + (float)cur[j] * w1[j] +
                          (float)nxt[j] * w2[j] + bb[j];
                o[j] = (_Float16)siluf(a);
            }
            const int lrow = r0 + r;
            *(half8*)(xc + (size_t)(row0 + lrow) * D_INNER + gcol) = o;
            // swizzled LDS: element chunk cg of row lrow at chunk cg ^ (lrow&7)
            *(half8*)(As_w + lrow * 128 + ((cg ^ (lrow & 7)) * 8)) = o;
            prev = cur;
            cur = nxt;
        }
        // MFMA on this panel (within-wave; compiler inserts lgkmcnt waits)
#pragma unroll
        for (int ks = 0; ks < 4; ks++) {
            half8 af[2], bf[2];
#pragma unroll
            for (int rt = 0; rt < 2; rt++)
                af[rt] = *(const half8*)(As_w + (rt * 16 + fr) * 128 +
                                         (((ks * 4 + q) ^ (fr & 7)) * 8));
#pragma unroll
            for (int ot = 0; ot < 2; ot++)
                bf[ot] = *(const half8*)(WBCT + (size_t)(ot * 16 + fr) * D_INNER +
                                         kbase + ks * 32 + q * 8);
#pragma unroll
            for (int rt = 0; rt < 2; rt++)
#pragma unroll
                for (int ot = 0; ot < 2; ot++)
                    acc[rt][ot] = __builtin_amdgcn_mfma_f32_16x16x32_f16(af[rt], bf[ot], acc[rt][ot], 0, 0, 0);
        }
    }

    __syncthreads();                       // all waves done reading As as f16
    float* red = (float*)As;               // [wid][row 32][out 32] = 4096 f32 (16 KB)
    float* btl = (float*)As + 4096;        // [row 32][out 32] = 1024 f32 (4 KB)
    const int er = (lane >> 4) * 4, ec = lane & 15;
#pragma unroll
    for (int rt = 0; rt < 2; rt++)
#pragma unroll
        for (int ot = 0; ot < 2; ot++)
#pragma unroll
            for (int rr = 0; rr < 4; rr++)
                red[wid * 1024 + (rt * 16 + er + rr) * 32 + ot * 16 + ec] = acc[rt][ot][rr];
    __syncthreads();
#pragma unroll
    for (int i = 0; i < 4; i++) {
        int idx = i * 256 + tid;           // (row<<5)|out
        float v = red[idx] + red[1024 + idx] + red[2048 + idx] + red[3072 + idx];
        btl[idx] = v;
        BtCt[(size_t)row0 * 32 + idx] = v; // (row0+row)*32+out == row0*32+idx
    }
    __syncthreads();
    if (tid < 32) {                        // 2 chunks x 16 states
        const int ch = tid >> 4, s = tid & 15;
        const float decay = decay_of(A, s);
        float st = 0.f;
#pragma unroll
        for (int r = 0; r < CHUNK; r++)
            st = st * decay + btl[(ch * 16 + r) * 32 + s];
        fin[((row0 >> 4) + ch) * 16 + s] = st;
    }
}

// -------------------------------- scan -------------------------------------
// phase 2: carry propagation across chunks. 1 block x 64 threads (b,s).
__global__ __launch_bounds__(64) void scan_p2(const float* __restrict__ fin,
                                              const float* __restrict__ A,
                                              float* __restrict__ carry) {
    int t = threadIdx.x;
    int b = t >> 4, s = t & 15;
    float decay = decay_of(A, s);
    float d16 = decay;
#pragma unroll
    for (int k = 0; k < 4; k++) d16 *= d16;     // decay^16
    float cy = 0.f;
#pragma unroll 8
    for (int c = 0; c < NCHUNK; c++) {
        int idx = ((b * NCHUNK) + c) * 16 + s;
        carry[idx] = cy;
        cy = cy * d16 + fin[idx];
    }
}

// phase 3 + y-fuse: replay chunk scan (lanes 0..15, Bt/Ct preloaded to regs)
// -> ys in LDS, then all 256 threads compute y = (ys + xc*D) * silu(res),
// overwriting xc (f16). 1024 blocks x 256 threads; block = chunk-task.
__global__ __launch_bounds__(256) void scan_p3_fuse(const float* __restrict__ BtCt,
                                                    const float* __restrict__ A,
                                                    const float* __restrict__ carry,
                                                    const float* __restrict__ D,
                                                    const _Float16* __restrict__ xr,
                                                    _Float16* __restrict__ xc) {
    __shared__ float ysl[CHUNK];
    const int task = blockIdx.x;
    const int b = task >> 8, c = task & (NCHUNK - 1);
    const int row0 = b * SEQ + c * CHUNK;
    const int tid = threadIdx.x;

    if (tid < 16) {
        const int s = tid;
        const float decay = decay_of(A, s);
        size_t r = (size_t)row0 * 32;
        float bt[CHUNK], ct[CHUNK];
#pragma unroll
        for (int j = 0; j < CHUNK; j++) {       // independent loads, ILP
            bt[j] = BtCt[r + (size_t)j * 32 + s];
            ct[j] = BtCt[r + (size_t)j * 32 + 16 + s];
        }
        float st = carry[task * 16 + s];
        float yv[CHUNK];
#pragma unroll
        for (int j = 0; j < CHUNK; j++) {       // serial FMA chain only
            st = st * decay + bt[j];
            yv[j] = st * ct[j];
        }
#pragma unroll
        for (int j = 0; j < CHUNK; j++) {       // 16 independent reduce chains
            float y = yv[j];
            y += __shfl_xor(y, 1, 16);
            y += __shfl_xor(y, 2, 16);
            y += __shfl_xor(y, 4, 16);
            y += __shfl_xor(y, 8, 16);
            if (s == 0) ysl[j] = y;
        }
    }
    __syncthreads();

#pragma unroll
    for (int it = 0; it < 16; it++) {
        int chunk = it * 256 + tid;            // 0..4095 (16 rows x 256 col-chunks)
        int rl = chunk >> 8;                   // row within chunk
        int colb = (chunk & 255) * 8;          // col offset (elements)
        size_t row = (size_t)(row0 + rl);
        float yv = ysl[rl];
        half8 x8 = *(const half8*)(xc + row * D_INNER + colb);
        half8 r8 = *(const half8*)(xr + row * 4096 + 2048 + colb);
        float4 d0 = *(const float4*)(D + colb);
        float4 d1 = *(const float4*)(D + colb + 4);
        half8 o;
        float dd[8] = {d0.x, d0.y, d0.z, d0.w, d1.x, d1.y, d1.z, d1.w};
#pragma unroll
        for (int j = 0; j < 8; j++) {
            float y = yv + (float)x8[j] * dd[j];
            o[j] = (_Float16)(y * siluf((float)r8[j]));
        }
        *(half8*)(xc + row * D_INNER + colb) = o;
    }
}

// ------------------------------- launcher ----------------------------------
extern "C" void kernel_launch(void* const* d_in, const int* in_sizes, int n_in,
                              void* d_out, int out_size, void* d_ws, size_t ws_size,
                              hipStream_t stream) {
    const float* x      = (const float*)d_in[0];
    const float* W_in   = (const float*)d_in[1];
    const float* conv_w = (const float*)d_in[2];
    const float* conv_b = (const float*)d_in[3];
    const float* W_B    = (const float*)d_in[4];
    const float* W_C    = (const float*)d_in[5];
    const float* A      = (const float*)d_in[6];
    const float* D      = (const float*)d_in[7];
    const float* W_out  = (const float*)d_in[8];
    float* out = (float*)d_out;

    char* ws = (char*)d_ws;
    size_t off = 0;
    auto alloc = [&](size_t bytes) { size_t o = off; off += (bytes + 255) & ~(size_t)255; return o; };
    _Float16* xh    = (_Float16*)(ws + alloc((size_t)NROWS * D_MODEL * 2));      // 33.5 MB
    _Float16* WinT  = (_Float16*)(ws + alloc((size_t)4096 * 1024 * 2));          //  8.4 MB
    _Float16* WoutT = (_Float16*)(ws + alloc((size_t)1024 * 2048 * 2));          //  4.2 MB
    _Float16* WBCT  = (_Float16*)(ws + alloc((size_t)32 * 2048 * 2));            //  0.13 MB
    _Float16* xr    = (_Float16*)(ws + alloc((size_t)NROWS * 4096 * 2));         //  134 MB
    _Float16* xc    = (_Float16*)(ws + alloc((size_t)NROWS * D_INNER * 2));      //   67 MB
    float*    BtCt  = (float*)(ws + alloc((size_t)NROWS * 32 * 4));              //    2 MB
    float*    fin   = (float*)(ws + alloc((size_t)NTASK * 16 * 4));              //  64 KB
    float*    carry = (float*)(ws + alloc((size_t)NTASK * 16 * 4));              //  64 KB

    // 1. conversions
    convert_f32_f16<<<(NROWS * D_MODEL) / (256 * 8), 256, 0, stream>>>(x, xh);
    transpose_to_f16<<<dim3(4096 / 32, 1024 / 32), dim3(32, 8), 0, stream>>>(W_in, WinT, 1024, 4096);
    transpose_to_f16<<<dim3(1024 / 32, 2048 / 32), dim3(32, 8), 0, stream>>>(W_out, WoutT, 2048, 1024);
    convert_wbct<<<(32 * 2048) / 256, 256, 0, stream>>>(W_B, W_C, WBCT);
    // 2. GEMM1: xr = x @ W_in  (two half-M launches: profiling visibility)
    gemm_tn<_Float16><<<dim3(4096 / 128, 64), 256, 0, stream>>>(xh, WinT, xr, NROWS / 2, 4096, 1024);
    gemm_tn<_Float16><<<dim3(4096 / 128, 64), 256, 0, stream>>>(xh + (size_t)8192 * 1024, WinT,
                                                                xr + (size_t)8192 * 4096, NROWS / 2, 4096, 1024);
    // 3. conv + silu + Bt/Ct + fin (fused, MFMA)
    conv_bc_fin<<<NROWS / 32, 256, 0, stream>>>(xr, conv_w, conv_b, WBCT, A, xc, BtCt, fin);
    // 4. scan phase 2
    scan_p2<<<1, 64, 0, stream>>>(fin, A, carry);
    // 5. scan phase 3 + y-fuse
    scan_p3_fuse<<<NTASK, 256, 0, stream>>>(BtCt, A, carry, D, xr, xc);
    // 6. GEMM2: out = y @ W_out
    gemm_tn<float><<<dim3(1024 / 128, NROWS / 128), 256, 0, stream>>>(xc, WoutT, out, NROWS, 1024, 2048);
}